// Round 12
// baseline (529.326 us; speedup 1.0000x reference)
//
#include <hip/hip_runtime.h>
#include <hip/hip_bf16.h>
#include <math.h>

// AtnConv (contextual attention) B=2, H=W=64, C=128, k=3.
// Score path fp32: Ds = skewed X2·X2^T (split-bf16 MFMA, Ds[r][(c-r)&4095]);
// invn; G = 9-tap diag stencil (vertical float4 reads from skew); Ps = pooled
// logits (skewed) + row softmax stats; A2 = diag stencil of softmax(Ps) bf16;
// Y = A2 @ X1 bf16 MFMA split-K.
// R12: all write-once streams (Ds, G, Ps, A2) use nontemporal stores to
// bypass L2 write-allocate (R8 falsified segment-coalescing, R11 falsified
// occupancy as the gemm_d binder). gemm_d back to R7 128x128 tile.
// NOTE: k_x1t after k_pool_stats — X1T region overlaps G within buf2.

constexpr int Hh = 64;
constexpr int Ww = 64;
constexpr int CDIM = 128;
constexpr int LDIM = Hh * Ww;   // 4096

typedef __attribute__((ext_vector_type(8))) short bf16x8;
typedef __attribute__((ext_vector_type(4))) float f32x4;
typedef __attribute__((ext_vector_type(2))) float f32x2;

// --------------------------------------------- split X2 into bf16 hi/lo parts
__global__ __launch_bounds__(256)
void k_split(const float* __restrict__ X, __hip_bfloat16* __restrict__ Xh,
             __hip_bfloat16* __restrict__ Xl) {
    const int i = (blockIdx.x * 256 + threadIdx.x) * 4;
    const float4 v = *(const float4*)(X + i);
    __hip_bfloat16 h[4], l[4];
    const float f[4] = {v.x, v.y, v.z, v.w};
    #pragma unroll
    for (int j = 0; j < 4; ++j) {
        h[j] = __float2bfloat16(f[j]);
        l[j] = __float2bfloat16(f[j] - __bfloat162float(h[j]));
    }
    *(ushort4*)(Xh + i) = *(ushort4*)h;
    *(ushort4*)(Xl + i) = *(ushort4*)l;
}

// -------- Ds = skewed X2·X2^T via 3-term split-bf16 MFMA; Ds[r][(c-r)&4095].
// Nontemporal scalar stores (write-once stream; L2 allocate bypass).
__global__ __launch_bounds__(256)
void k_gemm_d(const __hip_bfloat16* __restrict__ Xh,
              const __hip_bfloat16* __restrict__ Xl, float* __restrict__ Ds) {
    const int t = threadIdx.x;
    const int wave = t >> 6, lane = t & 63;
    const int quad = lane >> 4, l16 = lane & 15;
    const int bm = blockIdx.x * 128 + wave * 32;
    const int bn = blockIdx.y * 128;
    f32x4 acc[2][8] = {};
    for (int k0 = 0; k0 < CDIM; k0 += 32) {
        const int kq = k0 + quad * 8;
        bf16x8 ah[2], al[2], bh[8], bl[8];
        #pragma unroll
        for (int mi = 0; mi < 2; ++mi) {
            const size_t r = (size_t)(bm + mi * 16 + l16) * CDIM + kq;
            ah[mi] = *(const bf16x8*)(Xh + r);
            al[mi] = *(const bf16x8*)(Xl + r);
        }
        #pragma unroll
        for (int nf = 0; nf < 8; ++nf) {
            const size_t r = (size_t)(bn + nf * 16 + l16) * CDIM + kq;
            bh[nf] = *(const bf16x8*)(Xh + r);
            bl[nf] = *(const bf16x8*)(Xl + r);
        }
        #pragma unroll
        for (int mi = 0; mi < 2; ++mi)
            #pragma unroll
            for (int nf = 0; nf < 8; ++nf) {
                acc[mi][nf] = __builtin_amdgcn_mfma_f32_16x16x32_bf16(ah[mi], bh[nf], acc[mi][nf], 0, 0, 0);
                acc[mi][nf] = __builtin_amdgcn_mfma_f32_16x16x32_bf16(ah[mi], bl[nf], acc[mi][nf], 0, 0, 0);
                acc[mi][nf] = __builtin_amdgcn_mfma_f32_16x16x32_bf16(al[mi], bh[nf], acc[mi][nf], 0, 0, 0);
            }
    }
    #pragma unroll
    for (int mi = 0; mi < 2; ++mi)
        #pragma unroll
        for (int nf = 0; nf < 8; ++nf) {
            const int row = bm + mi * 16 + quad * 4;
            const int col = bn + nf * 16 + l16;
            #pragma unroll
            for (int r = 0; r < 4; ++r)
                __builtin_nontemporal_store(acc[mi][nf][r],
                    Ds + (size_t)(row + r) * LDIM + ((col - row - r) & (LDIM - 1)));
        }
}

// ---------------- invn[l] = 1/max(sqrt(sum diag-neigh),eps); diag = Ds[.][0]
__global__ void k_invnorm(const float* __restrict__ Ds, float* __restrict__ invn) {
    const int l = blockIdx.x * 256 + threadIdx.x;
    const int ly = l >> 6, lx = l & 63;
    float s = 0.f;
    #pragma unroll
    for (int ty = -1; ty <= 1; ++ty)
        #pragma unroll
        for (int tx = -1; tx <= 1; ++tx) {
            if ((unsigned)(ly + ty) < 64u && (unsigned)(lx + tx) < 64u) {
                const int q = l + ty * Ww + tx;
                s += Ds[(size_t)q * LDIM];
            }
        }
    invn[l] = 1.0f / fmaxf(sqrtf(s), 1e-4f);
}

// ---- G[x,l] = sum_t D[x+t,l+t] read vertically from skewed Ds. NT stores.
__global__ __launch_bounds__(256)
void k_gdiag(const float* __restrict__ Ds, float* __restrict__ G) {
    constexpr int T = 8;
    const int d0 = (blockIdx.x * 256 + threadIdx.x) * 4;
    const int x0 = blockIdx.y * T;
    const int xyc = x0 >> 6;
    const int xxb = x0 & 63;
    float acc[T][4] = {};
    #pragma unroll
    for (int c = 0; c < 3; ++c) {
        const int bc = c * 64 - 65;          // -65, -1, 63
        const int ty = c - 1;
        if ((unsigned)(xyc + ty) >= 64u) continue;
        float w[T + 2][4];
        #pragma unroll
        for (int u = 0; u < T + 2; ++u) {
            const int r = x0 + bc + u;
            if ((unsigned)r < (unsigned)LDIM) {
                const f32x4 v = *(const f32x4*)(Ds + (size_t)r * LDIM + d0);
                w[u][0] = v.x; w[u][1] = v.y; w[u][2] = v.z; w[u][3] = v.w;
            } else {
                w[u][0] = w[u][1] = w[u][2] = w[u][3] = 0.f;
            }
        }
        #pragma unroll
        for (int i = 0; i < T; ++i) {
            const int px = xxb + i;
            const int p  = x0 + i;
            #pragma unroll
            for (int j = 0; j < 4; ++j) {
                const int l  = (p + d0 + j) & (LDIM - 1);
                const int ly = l >> 6, lx = l & 63;
                if ((unsigned)(ly + ty) < 64u) {
                    float sv = acc[i][j];
                    if (px > 0 && lx > 0)   sv += w[i][j];
                    sv += w[i + 1][j];
                    if (px < 63 && lx < 63) sv += w[i + 2][j];
                    acc[i][j] = sv;
                }
            }
        }
    }
    #pragma unroll
    for (int i = 0; i < T; ++i) {
        const int x = x0 + i;
        const int l0i = (x + d0) & (LDIM - 1);
        float* base = G + (size_t)x * LDIM;
        if (l0i <= LDIM - 4) {
            if (!(l0i & 1)) {
                __builtin_nontemporal_store((f32x2){acc[i][0], acc[i][1]}, (f32x2*)(base + l0i));
                __builtin_nontemporal_store((f32x2){acc[i][2], acc[i][3]}, (f32x2*)(base + l0i + 2));
            } else {
                __builtin_nontemporal_store(acc[i][0], base + l0i);
                __builtin_nontemporal_store((f32x2){acc[i][1], acc[i][2]}, (f32x2*)(base + l0i + 1));
                __builtin_nontemporal_store(acc[i][3], base + l0i + 3);
            }
        } else {
            #pragma unroll
            for (int j = 0; j < 4; ++j)
                __builtin_nontemporal_store(acc[i][j], base + ((l0i + j) & (LDIM - 1)));
        }
    }
}

// ------- P[x,l] = (90/cnt)*invn[l]*sum_s G[x+s,l]; 4-col float4 vectorized.
// Output stored SKEWED via NT stores: Ps[x][(l-x)&4095] = P[x][l]. Row stats.
__global__ __launch_bounds__(256)
void k_pool_stats(const float* __restrict__ G, const float* __restrict__ invn,
                  float* __restrict__ Ps, float* __restrict__ rowm,
                  float* __restrict__ rowrz) {
    constexpr int T = 8;
    const int x0 = blockIdx.x * T;
    const int t  = threadIdx.x;
    const int xyc = x0 >> 6;
    const int xxb = x0 & 63;
    const int cy = 1 + (xyc > 0) + (xyc < 63);
    float sc[T];
    #pragma unroll
    for (int i = 0; i < T; ++i) {
        const int xx = xxb + i;
        sc[i] = 90.0f / (float)(cy * (1 + (xx > 0) + (xx < 63)));
    }
    float m[T], Z[T];
    #pragma unroll
    for (int i = 0; i < T; ++i) { m[i] = -1e30f; Z[i] = 0.f; }

    for (int ch = 0; ch < 4; ++ch) {
        const int l0 = ch * 1024 + t * 4;
        const f32x4 inl = *(const f32x4*)(invn + l0);
        f32x4 acc[T];
        #pragma unroll
        for (int i = 0; i < T; ++i) acc[i] = (f32x4){0.f, 0.f, 0.f, 0.f};
        #pragma unroll
        for (int c = 0; c < 3; ++c) {
            const int bc = c * 64 - 65;
            const int ty = c - 1;
            if ((unsigned)(xyc + ty) >= 64u) continue;
            f32x4 w[T + 2];
            #pragma unroll
            for (int u = 0; u < T + 2; ++u) {
                const int r = x0 + bc + u;
                w[u] = ((unsigned)r < (unsigned)LDIM)
                         ? *(const f32x4*)(G + (size_t)r * LDIM + l0)
                         : (f32x4){0.f, 0.f, 0.f, 0.f};
            }
            #pragma unroll
            for (int i = 0; i < T; ++i) {
                const int xx = xxb + i;
                if (xx > 0)  acc[i] += w[i];
                acc[i] += w[i + 1];
                if (xx < 63) acc[i] += w[i + 2];
            }
        }
        #pragma unroll
        for (int i = 0; i < T; ++i) {
            const f32x4 p = acc[i] * sc[i] * inl;
            const int x = x0 + i;
            const int c0 = (l0 - x) & (LDIM - 1);
            float* base = Ps + (size_t)x * LDIM;
            if (c0 <= LDIM - 4) {
                if (!(c0 & 1)) {
                    __builtin_nontemporal_store((f32x2){p.x, p.y}, (f32x2*)(base + c0));
                    __builtin_nontemporal_store((f32x2){p.z, p.w}, (f32x2*)(base + c0 + 2));
                } else {
                    __builtin_nontemporal_store(p.x, base + c0);
                    __builtin_nontemporal_store((f32x2){p.y, p.z}, (f32x2*)(base + c0 + 1));
                    __builtin_nontemporal_store(p.w, base + c0 + 3);
                }
            } else {
                __builtin_nontemporal_store(p.x, base + c0);
                __builtin_nontemporal_store(p.y, base + ((c0 + 1) & (LDIM - 1)));
                __builtin_nontemporal_store(p.z, base + ((c0 + 2) & (LDIM - 1)));
                __builtin_nontemporal_store(p.w, base + ((c0 + 3) & (LDIM - 1)));
            }
            const float mx4 = fmaxf(fmaxf(p.x, p.y), fmaxf(p.z, p.w));
            const float nm = fmaxf(m[i], mx4);
            Z[i] = Z[i] * __expf(m[i] - nm)
                 + __expf(p.x - nm) + __expf(p.y - nm)
                 + __expf(p.z - nm) + __expf(p.w - nm);
            m[i] = nm;
        }
    }
    __shared__ float sm[256], sz[256];
    for (int i = 0; i < T; ++i) {
        __syncthreads();
        sm[t] = m[i]; sz[t] = Z[i];
        __syncthreads();
        for (int off = 128; off > 0; off >>= 1) {
            if (t < off) {
                const float m2 = sm[t + off], z2 = sz[t + off];
                const float nm = fmaxf(sm[t], m2);
                sz[t] = sz[t] * __expf(sm[t] - nm) + z2 * __expf(m2 - nm);
                sm[t] = nm;
            }
            __syncthreads();
        }
        if (t == 0) { rowm[x0 + i] = sm[0]; rowrz[x0 + i] = 1.0f / sz[0]; }
    }
}

// ---- X1 [4096][128] fp32 -> X1T [128][4096] bf16 (LDS-tiled transpose)
// Launched AFTER k_pool_stats: X1T region overlaps G's tail in buf2.
__global__ __launch_bounds__(256)
void k_x1t(const float* __restrict__ X1, __hip_bfloat16* __restrict__ X1T) {
    __shared__ float tile[32][132];
    const int k0 = blockIdx.x * 32;
    const int t  = threadIdx.x;
    const int kr = t >> 3;
    const int c0 = (t & 7) * 16;
    #pragma unroll
    for (int j = 0; j < 4; ++j) {
        const float4 v = *(const float4*)(X1 + (size_t)(k0 + kr) * CDIM + c0 + 4 * j);
        tile[kr][c0 + 4 * j + 0] = v.x;
        tile[kr][c0 + 4 * j + 1] = v.y;
        tile[kr][c0 + 4 * j + 2] = v.z;
        tile[kr][c0 + 4 * j + 3] = v.w;
    }
    __syncthreads();
    const int c  = t >> 1;
    const int kh = (t & 1) * 16;
    __hip_bfloat16 outv[16];
    #pragma unroll
    for (int j = 0; j < 16; ++j)
        outv[j] = __float2bfloat16(tile[kh + j][c]);
    *(ushort4*)(X1T + (size_t)c * LDIM + k0 + kh)      = *(ushort4*)(outv);
    *(ushort4*)(X1T + (size_t)c * LDIM + k0 + kh + 4)  = *(ushort4*)(outv + 4);
    *(ushort4*)(X1T + (size_t)c * LDIM + k0 + kh + 8)  = *(ushort4*)(outv + 8);
    *(ushort4*)(X1T + (size_t)c * LDIM + k0 + kh + 12) = *(ushort4*)(outv + 12);
}

// ---- A2[p,q] = sum_t exp(P[p+t,q+t]-m)*rz. Reads skewed Ps vertically.
// NT stores (A2 is read next kernel from HBM-sized stream anyway).
__global__ __launch_bounds__(256)
void k_att2(const float* __restrict__ Ps, const float* __restrict__ rowm,
            const float* __restrict__ rowrz, __hip_bfloat16* __restrict__ A2) {
    constexpr int T = 8;
    const int d0 = (blockIdx.x * 256 + threadIdx.x) * 4;
    const int p0 = blockIdx.y * T;
    const int pyc = p0 >> 6;
    const int pxb = p0 & 63;
    float acc[T][4] = {};
    #pragma unroll
    for (int c = 0; c < 3; ++c) {
        const int bc = c * 64 - 65;          // -65, -1, 63
        const int ty = c - 1;
        if ((unsigned)(pyc + ty) >= 64u) continue;
        float e[T + 2][4];
        #pragma unroll
        for (int u = 0; u < T + 2; ++u) {
            const int r = p0 + bc + u;
            if ((unsigned)r < (unsigned)LDIM) {
                const f32x4 w = *(const f32x4*)(Ps + (size_t)r * LDIM + d0);
                const float mr = rowm[r], rzr = rowrz[r];
                e[u][0] = __expf(w.x - mr) * rzr;
                e[u][1] = __expf(w.y - mr) * rzr;
                e[u][2] = __expf(w.z - mr) * rzr;
                e[u][3] = __expf(w.w - mr) * rzr;
            } else {
                e[u][0] = e[u][1] = e[u][2] = e[u][3] = 0.f;
            }
        }
        #pragma unroll
        for (int i = 0; i < T; ++i) {
            const int px = pxb + i;
            const int p  = p0 + i;
            #pragma unroll
            for (int j = 0; j < 4; ++j) {
                const int q  = (p + d0 + j) & (LDIM - 1);
                const int qy = q >> 6, qx = q & 63;
                if ((unsigned)(qy + ty) < 64u) {
                    float sv = acc[i][j];
                    if (px > 0 && qx > 0)   sv += e[i][j];
                    sv += e[i + 1][j];
                    if (px < 63 && qx < 63) sv += e[i + 2][j];
                    acc[i][j] = sv;
                }
            }
        }
    }
    #pragma unroll
    for (int i = 0; i < T; ++i) {
        const int p = p0 + i;
        const int q0i = (p + d0) & (LDIM - 1);
        union { __hip_bfloat16 h[4]; unsigned short us[4]; unsigned int ui[2]; } cv;
        #pragma unroll
        for (int j = 0; j < 4; ++j) cv.h[j] = __float2bfloat16(acc[i][j]);
        unsigned short* bp = (unsigned short*)(A2 + (size_t)p * LDIM);
        if (q0i <= LDIM - 4) {
            if (!(q0i & 1)) {
                __builtin_nontemporal_store(cv.ui[0], (unsigned int*)(bp + q0i));
                __builtin_nontemporal_store(cv.ui[1], (unsigned int*)(bp + q0i + 2));
            } else {
                __builtin_nontemporal_store(cv.us[0], bp + q0i);
                __builtin_nontemporal_store(
                    (unsigned int)cv.us[1] | ((unsigned int)cv.us[2] << 16),
                    (unsigned int*)(bp + q0i + 1));
                __builtin_nontemporal_store(cv.us[3], bp + q0i + 3);
            }
        } else {
            #pragma unroll
            for (int j = 0; j < 4; ++j)
                __builtin_nontemporal_store(cv.us[j], bp + ((q0i + j) & (LDIM - 1)));
        }
    }
}

// ---------------- Y += A2 @ X1 (bf16 MFMA, split-K=8, atomic f32 epilogue)
__global__ __launch_bounds__(256)
void k_gemm_y(const __hip_bfloat16* __restrict__ A2b,
              const __hip_bfloat16* __restrict__ X1T, float* __restrict__ Y) {
    const int t = threadIdx.x;
    const int wave = t >> 6, lane = t & 63;
    const int quad = lane >> 4, l16 = lane & 15;
    const int bm = blockIdx.x * 128 + wave * 32;
    const int kc = blockIdx.y * 512;
    f32x4 acc[2][8] = {};
    for (int ks = 0; ks < 512; ks += 32) {
        const int kq = kc + ks + quad * 8;
        bf16x8 a[2], b[8];
        #pragma unroll
        for (int mi = 0; mi < 2; ++mi)
            a[mi] = *(const bf16x8*)(A2b + (size_t)(bm + mi * 16 + l16) * LDIM + kq);
        #pragma unroll
        for (int nf = 0; nf < 8; ++nf)
            b[nf] = *(const bf16x8*)(X1T + (size_t)(nf * 16 + l16) * LDIM + kq);
        #pragma unroll
        for (int mi = 0; mi < 2; ++mi)
            #pragma unroll
            for (int nf = 0; nf < 8; ++nf)
                acc[mi][nf] = __builtin_amdgcn_mfma_f32_16x16x32_bf16(a[mi], b[nf], acc[mi][nf], 0, 0, 0);
    }
    #pragma unroll
    for (int mi = 0; mi < 2; ++mi)
        #pragma unroll
        for (int nf = 0; nf < 8; ++nf)
            #pragma unroll
            for (int r = 0; r < 4; ++r)
                atomicAdd(Y + (size_t)(bm + mi * 16 + quad * 4 + r) * CDIM + nf * 16 + l16,
                          acc[mi][nf][r]);
}

extern "C" void kernel_launch(void* const* d_in, const int* in_sizes, int n_in,
                              void* d_out, int out_size, void* d_ws, size_t ws_size,
                              hipStream_t stream) {
    const float* x1 = (const float*)d_in[0];
    const float* x2 = (const float*)d_in[1];
    float* out = (float*)d_out;

    const size_t MATB = (size_t)LDIM * LDIM * sizeof(float);   // 64 MB
    char* ws = (char*)d_ws;
    float* buf1  = (float*)ws;                         // Ds, then Ps (fp32)
    char*  buf2c = ws + MATB;                          // multi-use 64 MB
    float* buf2  = (float*)buf2c;                      // G (fp32)
    __hip_bfloat16* X2h = (__hip_bfloat16*)buf2c;                    // 1 MB
    __hip_bfloat16* X2l = (__hip_bfloat16*)(buf2c + (size_t)LDIM * CDIM * 2);
    __hip_bfloat16* A2b = (__hip_bfloat16*)buf2c;                    // 32 MB
    __hip_bfloat16* X1T = (__hip_bfloat16*)(buf2c + MATB / 2);       // 1 MB
    float* invn  = (float*)(ws + 2 * MATB);
    float* rowm  = invn + LDIM;
    float* rowrz = rowm + LDIM;

    const int B = in_sizes[0] / (LDIM * CDIM);

    hipMemsetAsync(d_out, 0, (size_t)out_size * sizeof(float), stream);

    for (int b = 0; b < B; ++b) {
        const float* X2b_ = x2 + (size_t)b * LDIM * CDIM;
        const float* X1b_ = x1 + (size_t)b * LDIM * CDIM;
        float* Yb = out + (size_t)b * LDIM * CDIM;

        k_split     <<<LDIM * CDIM / 1024, 256, 0, stream>>>(X2b_, X2h, X2l);
        k_gemm_d    <<<dim3(LDIM / 128, LDIM / 128), 256, 0, stream>>>(X2h, X2l, buf1);
        k_invnorm   <<<LDIM / 256, 256, 0, stream>>>(buf1, invn);
        k_gdiag     <<<dim3(LDIM / 1024, LDIM / 8), 256, 0, stream>>>(buf1, buf2);
        k_pool_stats<<<LDIM / 8, 256, 0, stream>>>(buf2, invn, buf1, rowm, rowrz);
        k_x1t       <<<LDIM / 32, 256, 0, stream>>>(X1b_, X1T);
        k_att2      <<<dim3(LDIM / 1024, LDIM / 8), 256, 0, stream>>>(buf1, rowm, rowrz, A2b);
        k_gemm_y    <<<dim3(LDIM / 128, 8), 256, 0, stream>>>(A2b, X1T, Yb);
    }
}

// Round 13
// 486.722 us; speedup vs baseline: 1.0875x; 1.0875x over previous
//
#include <hip/hip_runtime.h>
#include <hip/hip_bf16.h>
#include <math.h>

// AtnConv (contextual attention) B=2, H=W=64, C=128, k=3.
// Score path fp32: Ds = skewed X2·X2^T (split-bf16 MFMA, Ds[r][(c-r)&4095]);
// invn; G = 9-tap diag stencil (vertical float4 reads from skew); Ps = pooled
// logits (skewed) + row softmax stats; A2 = diag stencil of softmax(Ps) bf16;
// Y = A2 @ X1 bf16 MFMA split-K.
// R13: gemm_d on 32x32x16 MFMA — C-layout gives 2x128B store segments/instr
// (vs 4x64B with 16x16), half the MFMA instrs. NT stores reverted (R12:
// WRITE_SIZE 67->120MB, L2 write-combining was helping). Rest = R7 config.
// NOTE: k_x1t after k_pool_stats — X1T region overlaps G within buf2.

constexpr int Hh = 64;
constexpr int Ww = 64;
constexpr int CDIM = 128;
constexpr int LDIM = Hh * Ww;   // 4096

typedef __attribute__((ext_vector_type(8))) short bf16x8;
typedef __attribute__((ext_vector_type(4))) float f32x4;
typedef __attribute__((ext_vector_type(16))) float f32x16;

// --------------------------------------------- split X2 into bf16 hi/lo parts
__global__ __launch_bounds__(256)
void k_split(const float* __restrict__ X, __hip_bfloat16* __restrict__ Xh,
             __hip_bfloat16* __restrict__ Xl) {
    const int i = (blockIdx.x * 256 + threadIdx.x) * 4;
    const float4 v = *(const float4*)(X + i);
    __hip_bfloat16 h[4], l[4];
    const float f[4] = {v.x, v.y, v.z, v.w};
    #pragma unroll
    for (int j = 0; j < 4; ++j) {
        h[j] = __float2bfloat16(f[j]);
        l[j] = __float2bfloat16(f[j] - __bfloat162float(h[j]));
    }
    *(ushort4*)(Xh + i) = *(ushort4*)h;
    *(ushort4*)(Xl + i) = *(ushort4*)l;
}

// -------- Ds = skewed X2·X2^T via 3-term split-bf16 32x32x16 MFMA.
// Wave tile 32(M)x128(N); C frag: col=lane&31, row=(reg&3)+8*(reg>>2)+4*half.
__global__ __launch_bounds__(256)
void k_gemm_d(const __hip_bfloat16* __restrict__ Xh,
              const __hip_bfloat16* __restrict__ Xl, float* __restrict__ Ds) {
    const int t = threadIdx.x;
    const int wave = t >> 6, lane = t & 63;
    const int half = lane >> 5, l32 = lane & 31;
    const int bm = blockIdx.x * 128 + wave * 32;
    const int bn = blockIdx.y * 128;
    f32x16 acc[4] = {};
    for (int k0 = 0; k0 < CDIM; k0 += 16) {
        const int kq = k0 + half * 8;
        const size_t ra = (size_t)(bm + l32) * CDIM + kq;
        const bf16x8 ah = *(const bf16x8*)(Xh + ra);
        const bf16x8 al = *(const bf16x8*)(Xl + ra);
        #pragma unroll
        for (int nf = 0; nf < 4; ++nf) {
            const size_t rb = (size_t)(bn + nf * 32 + l32) * CDIM + kq;
            const bf16x8 bh = *(const bf16x8*)(Xh + rb);
            const bf16x8 bl = *(const bf16x8*)(Xl + rb);
            acc[nf] = __builtin_amdgcn_mfma_f32_32x32x16_bf16(ah, bh, acc[nf], 0, 0, 0);
            acc[nf] = __builtin_amdgcn_mfma_f32_32x32x16_bf16(ah, bl, acc[nf], 0, 0, 0);
            acc[nf] = __builtin_amdgcn_mfma_f32_32x32x16_bf16(al, bh, acc[nf], 0, 0, 0);
        }
    }
    #pragma unroll
    for (int nf = 0; nf < 4; ++nf)
        #pragma unroll
        for (int reg = 0; reg < 16; ++reg) {
            const int row = bm + (reg & 3) + 8 * (reg >> 2) + 4 * half;
            const int col = bn + nf * 32 + l32;
            Ds[(size_t)row * LDIM + ((col - row) & (LDIM - 1))] = acc[nf][reg];
        }
}

// ---------------- invn[l] = 1/max(sqrt(sum diag-neigh),eps); diag = Ds[.][0]
__global__ void k_invnorm(const float* __restrict__ Ds, float* __restrict__ invn) {
    const int l = blockIdx.x * 256 + threadIdx.x;
    const int ly = l >> 6, lx = l & 63;
    float s = 0.f;
    #pragma unroll
    for (int ty = -1; ty <= 1; ++ty)
        #pragma unroll
        for (int tx = -1; tx <= 1; ++tx) {
            if ((unsigned)(ly + ty) < 64u && (unsigned)(lx + tx) < 64u) {
                const int q = l + ty * Ww + tx;
                s += Ds[(size_t)q * LDIM];
            }
        }
    invn[l] = 1.0f / fmaxf(sqrtf(s), 1e-4f);
}

// ---- G[x,l] = sum_t D[x+t,l+t] read vertically from skewed Ds.
__global__ __launch_bounds__(256)
void k_gdiag(const float* __restrict__ Ds, float* __restrict__ G) {
    constexpr int T = 8;
    const int d0 = (blockIdx.x * 256 + threadIdx.x) * 4;
    const int x0 = blockIdx.y * T;
    const int xyc = x0 >> 6;
    const int xxb = x0 & 63;
    float acc[T][4] = {};
    #pragma unroll
    for (int c = 0; c < 3; ++c) {
        const int bc = c * 64 - 65;          // -65, -1, 63
        const int ty = c - 1;
        if ((unsigned)(xyc + ty) >= 64u) continue;
        float w[T + 2][4];
        #pragma unroll
        for (int u = 0; u < T + 2; ++u) {
            const int r = x0 + bc + u;
            if ((unsigned)r < (unsigned)LDIM) {
                const f32x4 v = *(const f32x4*)(Ds + (size_t)r * LDIM + d0);
                w[u][0] = v.x; w[u][1] = v.y; w[u][2] = v.z; w[u][3] = v.w;
            } else {
                w[u][0] = w[u][1] = w[u][2] = w[u][3] = 0.f;
            }
        }
        #pragma unroll
        for (int i = 0; i < T; ++i) {
            const int px = xxb + i;
            const int p  = x0 + i;
            #pragma unroll
            for (int j = 0; j < 4; ++j) {
                const int l  = (p + d0 + j) & (LDIM - 1);
                const int ly = l >> 6, lx = l & 63;
                if ((unsigned)(ly + ty) < 64u) {
                    float sv = acc[i][j];
                    if (px > 0 && lx > 0)   sv += w[i][j];
                    sv += w[i + 1][j];
                    if (px < 63 && lx < 63) sv += w[i + 2][j];
                    acc[i][j] = sv;
                }
            }
        }
    }
    #pragma unroll
    for (int i = 0; i < T; ++i) {
        const int x = x0 + i;
        const int l0i = (x + d0) & (LDIM - 1);
        float* base = G + (size_t)x * LDIM;
        if (l0i <= LDIM - 4) {
            if (!(l0i & 1)) {
                *(float2*)(base + l0i)     = make_float2(acc[i][0], acc[i][1]);
                *(float2*)(base + l0i + 2) = make_float2(acc[i][2], acc[i][3]);
            } else {
                base[l0i] = acc[i][0];
                *(float2*)(base + l0i + 1) = make_float2(acc[i][1], acc[i][2]);
                base[l0i + 3] = acc[i][3];
            }
        } else {
            #pragma unroll
            for (int j = 0; j < 4; ++j)
                base[(l0i + j) & (LDIM - 1)] = acc[i][j];
        }
    }
}

// ------- P[x,l] = (90/cnt)*invn[l]*sum_s G[x+s,l]; 4-col float4 vectorized.
// Output stored SKEWED: Ps[x][(l-x)&4095] = P[x][l]. Row softmax stats too.
__global__ __launch_bounds__(256)
void k_pool_stats(const float* __restrict__ G, const float* __restrict__ invn,
                  float* __restrict__ Ps, float* __restrict__ rowm,
                  float* __restrict__ rowrz) {
    constexpr int T = 8;
    const int x0 = blockIdx.x * T;
    const int t  = threadIdx.x;
    const int xyc = x0 >> 6;
    const int xxb = x0 & 63;
    const int cy = 1 + (xyc > 0) + (xyc < 63);
    float sc[T];
    #pragma unroll
    for (int i = 0; i < T; ++i) {
        const int xx = xxb + i;
        sc[i] = 90.0f / (float)(cy * (1 + (xx > 0) + (xx < 63)));
    }
    float m[T], Z[T];
    #pragma unroll
    for (int i = 0; i < T; ++i) { m[i] = -1e30f; Z[i] = 0.f; }

    for (int ch = 0; ch < 4; ++ch) {
        const int l0 = ch * 1024 + t * 4;
        const f32x4 inl = *(const f32x4*)(invn + l0);
        f32x4 acc[T];
        #pragma unroll
        for (int i = 0; i < T; ++i) acc[i] = (f32x4){0.f, 0.f, 0.f, 0.f};
        #pragma unroll
        for (int c = 0; c < 3; ++c) {
            const int bc = c * 64 - 65;
            const int ty = c - 1;
            if ((unsigned)(xyc + ty) >= 64u) continue;
            f32x4 w[T + 2];
            #pragma unroll
            for (int u = 0; u < T + 2; ++u) {
                const int r = x0 + bc + u;
                w[u] = ((unsigned)r < (unsigned)LDIM)
                         ? *(const f32x4*)(G + (size_t)r * LDIM + l0)
                         : (f32x4){0.f, 0.f, 0.f, 0.f};
            }
            #pragma unroll
            for (int i = 0; i < T; ++i) {
                const int xx = xxb + i;
                if (xx > 0)  acc[i] += w[i];
                acc[i] += w[i + 1];
                if (xx < 63) acc[i] += w[i + 2];
            }
        }
        #pragma unroll
        for (int i = 0; i < T; ++i) {
            const f32x4 p = acc[i] * sc[i] * inl;
            const int x = x0 + i;
            const int c0 = (l0 - x) & (LDIM - 1);
            float* base = Ps + (size_t)x * LDIM;
            if (c0 <= LDIM - 4) {
                if (!(c0 & 1)) {
                    *(float2*)(base + c0)     = make_float2(p.x, p.y);
                    *(float2*)(base + c0 + 2) = make_float2(p.z, p.w);
                } else {
                    base[c0] = p.x;
                    *(float2*)(base + c0 + 1) = make_float2(p.y, p.z);
                    base[c0 + 3] = p.w;
                }
            } else {
                base[c0] = p.x;
                base[(c0 + 1) & (LDIM - 1)] = p.y;
                base[(c0 + 2) & (LDIM - 1)] = p.z;
                base[(c0 + 3) & (LDIM - 1)] = p.w;
            }
            const float mx4 = fmaxf(fmaxf(p.x, p.y), fmaxf(p.z, p.w));
            const float nm = fmaxf(m[i], mx4);
            Z[i] = Z[i] * __expf(m[i] - nm)
                 + __expf(p.x - nm) + __expf(p.y - nm)
                 + __expf(p.z - nm) + __expf(p.w - nm);
            m[i] = nm;
        }
    }
    __shared__ float sm[256], sz[256];
    for (int i = 0; i < T; ++i) {
        __syncthreads();
        sm[t] = m[i]; sz[t] = Z[i];
        __syncthreads();
        for (int off = 128; off > 0; off >>= 1) {
            if (t < off) {
                const float m2 = sm[t + off], z2 = sz[t + off];
                const float nm = fmaxf(sm[t], m2);
                sz[t] = sz[t] * __expf(sm[t] - nm) + z2 * __expf(m2 - nm);
                sm[t] = nm;
            }
            __syncthreads();
        }
        if (t == 0) { rowm[x0 + i] = sm[0]; rowrz[x0 + i] = 1.0f / sz[0]; }
    }
}

// ---- X1 [4096][128] fp32 -> X1T [128][4096] bf16 (LDS-tiled transpose)
// Launched AFTER k_pool_stats: X1T region overlaps G's tail in buf2.
__global__ __launch_bounds__(256)
void k_x1t(const float* __restrict__ X1, __hip_bfloat16* __restrict__ X1T) {
    __shared__ float tile[32][132];
    const int k0 = blockIdx.x * 32;
    const int t  = threadIdx.x;
    const int kr = t >> 3;
    const int c0 = (t & 7) * 16;
    #pragma unroll
    for (int j = 0; j < 4; ++j) {
        const float4 v = *(const float4*)(X1 + (size_t)(k0 + kr) * CDIM + c0 + 4 * j);
        tile[kr][c0 + 4 * j + 0] = v.x;
        tile[kr][c0 + 4 * j + 1] = v.y;
        tile[kr][c0 + 4 * j + 2] = v.z;
        tile[kr][c0 + 4 * j + 3] = v.w;
    }
    __syncthreads();
    const int c  = t >> 1;
    const int kh = (t & 1) * 16;
    __hip_bfloat16 outv[16];
    #pragma unroll
    for (int j = 0; j < 16; ++j)
        outv[j] = __float2bfloat16(tile[kh + j][c]);
    *(ushort4*)(X1T + (size_t)c * LDIM + k0 + kh)      = *(ushort4*)(outv);
    *(ushort4*)(X1T + (size_t)c * LDIM + k0 + kh + 4)  = *(ushort4*)(outv + 4);
    *(ushort4*)(X1T + (size_t)c * LDIM + k0 + kh + 8)  = *(ushort4*)(outv + 8);
    *(ushort4*)(X1T + (size_t)c * LDIM + k0 + kh + 12) = *(ushort4*)(outv + 12);
}

// ---- A2[p,q] = sum_t exp(P[p+t,q+t]-m)*rz. Reads skewed Ps vertically.
__global__ __launch_bounds__(256)
void k_att2(const float* __restrict__ Ps, const float* __restrict__ rowm,
            const float* __restrict__ rowrz, __hip_bfloat16* __restrict__ A2) {
    constexpr int T = 8;
    const int d0 = (blockIdx.x * 256 + threadIdx.x) * 4;
    const int p0 = blockIdx.y * T;
    const int pyc = p0 >> 6;
    const int pxb = p0 & 63;
    float acc[T][4] = {};
    #pragma unroll
    for (int c = 0; c < 3; ++c) {
        const int bc = c * 64 - 65;          // -65, -1, 63
        const int ty = c - 1;
        if ((unsigned)(pyc + ty) >= 64u) continue;
        float e[T + 2][4];
        #pragma unroll
        for (int u = 0; u < T + 2; ++u) {
            const int r = p0 + bc + u;
            if ((unsigned)r < (unsigned)LDIM) {
                const f32x4 w = *(const f32x4*)(Ps + (size_t)r * LDIM + d0);
                const float mr = rowm[r], rzr = rowrz[r];
                e[u][0] = __expf(w.x - mr) * rzr;
                e[u][1] = __expf(w.y - mr) * rzr;
                e[u][2] = __expf(w.z - mr) * rzr;
                e[u][3] = __expf(w.w - mr) * rzr;
            } else {
                e[u][0] = e[u][1] = e[u][2] = e[u][3] = 0.f;
            }
        }
        #pragma unroll
        for (int i = 0; i < T; ++i) {
            const int px = pxb + i;
            const int p  = p0 + i;
            #pragma unroll
            for (int j = 0; j < 4; ++j) {
                const int q  = (p + d0 + j) & (LDIM - 1);
                const int qy = q >> 6, qx = q & 63;
                if ((unsigned)(qy + ty) < 64u) {
                    float sv = acc[i][j];
                    if (px > 0 && qx > 0)   sv += e[i][j];
                    sv += e[i + 1][j];
                    if (px < 63 && qx < 63) sv += e[i + 2][j];
                    acc[i][j] = sv;
                }
            }
        }
    }
    #pragma unroll
    for (int i = 0; i < T; ++i) {
        const int p = p0 + i;
        const int q0i = (p + d0) & (LDIM - 1);
        union { __hip_bfloat16 h[4]; unsigned short us[4]; unsigned int ui[2]; } cv;
        #pragma unroll
        for (int j = 0; j < 4; ++j) cv.h[j] = __float2bfloat16(acc[i][j]);
        unsigned short* bp = (unsigned short*)(A2 + (size_t)p * LDIM);
        if (q0i <= LDIM - 4) {
            if (!(q0i & 1)) {
                *(unsigned int*)(bp + q0i)     = cv.ui[0];
                *(unsigned int*)(bp + q0i + 2) = cv.ui[1];
            } else {
                bp[q0i] = cv.us[0];
                *(unsigned int*)(bp + q0i + 1) =
                    (unsigned int)cv.us[1] | ((unsigned int)cv.us[2] << 16);
                bp[q0i + 3] = cv.us[3];
            }
        } else {
            #pragma unroll
            for (int j = 0; j < 4; ++j)
                bp[(q0i + j) & (LDIM - 1)] = cv.us[j];
        }
    }
}

// ---------------- Y += A2 @ X1 (bf16 MFMA, split-K=8, atomic f32 epilogue)
__global__ __launch_bounds__(256)
void k_gemm_y(const __hip_bfloat16* __restrict__ A2b,
              const __hip_bfloat16* __restrict__ X1T, float* __restrict__ Y) {
    const int t = threadIdx.x;
    const int wave = t >> 6, lane = t & 63;
    const int quad = lane >> 4, l16 = lane & 15;
    const int bm = blockIdx.x * 128 + wave * 32;
    const int kc = blockIdx.y * 512;
    f32x4 acc[2][8] = {};
    for (int ks = 0; ks < 512; ks += 32) {
        const int kq = kc + ks + quad * 8;
        bf16x8 a[2], b[8];
        #pragma unroll
        for (int mi = 0; mi < 2; ++mi)
            a[mi] = *(const bf16x8*)(A2b + (size_t)(bm + mi * 16 + l16) * LDIM + kq);
        #pragma unroll
        for (int nf = 0; nf < 8; ++nf)
            b[nf] = *(const bf16x8*)(X1T + (size_t)(nf * 16 + l16) * LDIM + kq);
        #pragma unroll
        for (int mi = 0; mi < 2; ++mi)
            #pragma unroll
            for (int nf = 0; nf < 8; ++nf)
                acc[mi][nf] = __builtin_amdgcn_mfma_f32_16x16x32_bf16(a[mi], b[nf], acc[mi][nf], 0, 0, 0);
    }
    #pragma unroll
    for (int mi = 0; mi < 2; ++mi)
        #pragma unroll
        for (int nf = 0; nf < 8; ++nf)
            #pragma unroll
            for (int r = 0; r < 4; ++r)
                atomicAdd(Y + (size_t)(bm + mi * 16 + quad * 4 + r) * CDIM + nf * 16 + l16,
                          acc[mi][nf][r]);
}

extern "C" void kernel_launch(void* const* d_in, const int* in_sizes, int n_in,
                              void* d_out, int out_size, void* d_ws, size_t ws_size,
                              hipStream_t stream) {
    const float* x1 = (const float*)d_in[0];
    const float* x2 = (const float*)d_in[1];
    float* out = (float*)d_out;

    const size_t MATB = (size_t)LDIM * LDIM * sizeof(float);   // 64 MB
    char* ws = (char*)d_ws;
    float* buf1  = (float*)ws;                         // Ds, then Ps (fp32)
    char*  buf2c = ws + MATB;                          // multi-use 64 MB
    float* buf2  = (float*)buf2c;                      // G (fp32)
    __hip_bfloat16* X2h = (__hip_bfloat16*)buf2c;                    // 1 MB
    __hip_bfloat16* X2l = (__hip_bfloat16*)(buf2c + (size_t)LDIM * CDIM * 2);
    __hip_bfloat16* A2b = (__hip_bfloat16*)buf2c;                    // 32 MB
    __hip_bfloat16* X1T = (__hip_bfloat16*)(buf2c + MATB / 2);       // 1 MB
    float* invn  = (float*)(ws + 2 * MATB);
    float* rowm  = invn + LDIM;
    float* rowrz = rowm + LDIM;

    const int B = in_sizes[0] / (LDIM * CDIM);

    hipMemsetAsync(d_out, 0, (size_t)out_size * sizeof(float), stream);

    for (int b = 0; b < B; ++b) {
        const float* X2b_ = x2 + (size_t)b * LDIM * CDIM;
        const float* X1b_ = x1 + (size_t)b * LDIM * CDIM;
        float* Yb = out + (size_t)b * LDIM * CDIM;

        k_split     <<<LDIM * CDIM / 1024, 256, 0, stream>>>(X2b_, X2h, X2l);
        k_gemm_d    <<<dim3(LDIM / 128, LDIM / 128), 256, 0, stream>>>(X2h, X2l, buf1);
        k_invnorm   <<<LDIM / 256, 256, 0, stream>>>(buf1, invn);
        k_gdiag     <<<dim3(LDIM / 1024, LDIM / 8), 256, 0, stream>>>(buf1, buf2);
        k_pool_stats<<<LDIM / 8, 256, 0, stream>>>(buf2, invn, buf1, rowm, rowrz);
        k_x1t       <<<LDIM / 32, 256, 0, stream>>>(X1b_, X1T);
        k_att2      <<<dim3(LDIM / 1024, LDIM / 8), 256, 0, stream>>>(buf1, rowm, rowrz, A2b);
        k_gemm_y    <<<dim3(LDIM / 128, 8), 256, 0, stream>>>(A2b, X1T, Yb);
    }
}